// Round 12
// baseline (184.676 us; speedup 1.0000x reference)
//
#include <hip/hip_runtime.h>
#include <math.h>

#define D_INNER 5120
#define DT_RANK 160
#define N_STATE 16
#define BATCH   256
#define KTOT    192               // 160 (dt_low) | 16 (B) | 16 (C)

// ---- K1 config: 256-thr blocks, 4 waves x 40-dd chunks, intra-block reduce ----
#define BGRP    8                 // batches per block
#define NBG     (BATCH / BGRP)    // 32
#define DDBLK   160               // dd per block (4 waves x 40)
#define NDDB    (D_INNER / DDBLK) // 32 -> SPLIT partials
#define SPLIT   32

// ---- K3 config: FUSED, 4 batches/block, grid (20,64)=1280 blocks ----
#define K3_BT   4

// ---- workspace layout (float offsets) ----
#define OFF_T     0
#define SZ_T      (BATCH * KTOT)                  // 49,152
#define OFF_P     (OFF_T + SZ_T)
#define SZ_P      (SPLIT * BATCH * KTOT)          // 1,572,864 (6.3 MB)
#define OFF_SBC   (OFF_P + SZ_P)                  // sbc[b] = sum_n T[b][160+n]*T[b][176+n]

// ---------------------------------------------------------------------------
// K1: projection GEMM partials (unchanged, ~10 us).
// ---------------------------------------------------------------------------
__global__ __launch_bounds__(256) void k1_gemm(const float* __restrict__ x,
                                               const float* __restrict__ Wdtlow,
                                               const float* __restrict__ WB,
                                               const float* __restrict__ WC,
                                               float* __restrict__ ws) {
    __shared__ float lds[4 * BGRP * KTOT];   // 6144 floats = 24 KB
    const int tid  = threadIdx.x;
    const int lane = tid & 63;
    const int wv   = tid >> 6;               // wave 0..3
    const int b0   = blockIdx.x * BGRP;
    const int ddB  = blockIdx.y * DDBLK;

    float* xs = lds;
    for (int j = tid; j < (BGRP * DDBLK) / 4; j += 256) {   // 320 float4
        int i  = j / (DDBLK / 4);
        int c4 = j % (DDBLK / 4);
        float4 v = *(const float4*)(x + (size_t)(b0 + i) * D_INNER + ddB + c4 * 4);
        *(float4*)(xs + i * DDBLK + c4 * 4) = v;
    }
    __syncthreads();

    const int dd0 = wv * 40;
    const float* p0 = Wdtlow + (size_t)(ddB + dd0) * DT_RANK + lane;
    const float* p1 = p0 + 64;
    const float* p2;
    int st2;
    if (lane < 32)      { p2 = p0 + 128;                                          st2 = DT_RANK; }
    else if (lane < 48) { p2 = WB + (size_t)(ddB + dd0) * N_STATE + (lane - 32);  st2 = N_STATE; }
    else                { p2 = WC + (size_t)(ddB + dd0) * N_STATE + (lane - 48);  st2 = N_STATE; }

    float acc0[BGRP], acc1[BGRP], acc2[BGRP];
#pragma unroll
    for (int i = 0; i < BGRP; ++i) { acc0[i] = 0.f; acc1[i] = 0.f; acc2[i] = 0.f; }

#pragma unroll 2
    for (int g = 0; g < 10; ++g) {           // 4 dd per group
        float w0[4], w1[4], w2[4];
#pragma unroll
        for (int u = 0; u < 4; ++u) {
            int dd = g * 4 + u;
            w0[u] = p0[(size_t)dd * DT_RANK];
            w1[u] = p1[(size_t)dd * DT_RANK];
            w2[u] = p2[(size_t)dd * st2];
        }
#pragma unroll
        for (int i = 0; i < BGRP; ++i) {
            float4 xv = *(const float4*)(xs + i * DDBLK + dd0 + g * 4);
            acc0[i] += xv.x * w0[0] + xv.y * w0[1] + xv.z * w0[2] + xv.w * w0[3];
            acc1[i] += xv.x * w1[0] + xv.y * w1[1] + xv.z * w1[2] + xv.w * w1[3];
            acc2[i] += xv.x * w2[0] + xv.y * w2[1] + xv.z * w2[2] + xv.w * w2[3];
        }
    }
    __syncthreads();

#pragma unroll
    for (int i = 0; i < BGRP; ++i) {
        float* r = lds + wv * (BGRP * KTOT) + i * KTOT;
        r[lane]       = acc0[i];
        r[lane + 64]  = acc1[i];
        r[lane + 128] = acc2[i];
    }
    __syncthreads();

    float* P = ws + OFF_P + (size_t)blockIdx.y * (BATCH * KTOT) + (size_t)b0 * KTOT;
#pragma unroll
    for (int r = 0; r < 6; ++r) {
        int idx = tid + r * 256;
        P[idx] = lds[idx] + lds[idx + 1536] + lds[idx + 3072] + lds[idx + 4608];
    }
}

// ---------------------------------------------------------------------------
// K2: reduce split-K partials -> T[256][192], plus hoisted sbc[b]. (unchanged)
// ---------------------------------------------------------------------------
__global__ __launch_bounds__(192) void k2_reduce(float* __restrict__ ws) {
    __shared__ float ts[KTOT];
    const int b   = blockIdx.x;
    const int col = threadIdx.x;
    const float* P = ws + OFF_P + (size_t)b * KTOT + col;
    float a = 0.f;
#pragma unroll
    for (int s = 0; s < SPLIT; ++s) a += P[(size_t)s * (BATCH * KTOT)];
    ws[OFF_T + b * KTOT + col] = a;
    ts[col] = a;
    __syncthreads();
    if (col == 0) {
        float s2 = 0.f;
#pragma unroll
        for (int n = 0; n < N_STATE; ++n) s2 += ts[160 + n] * ts[176 + n];
        ws[OFF_SBC + b] = s2;
    }
}

// ---------------------------------------------------------------------------
// K3: FUSED GEMM + scan — r4 compute + coalesced h0 via PIPELINED per-batch
// DMA staging. Design synthesis from the 12-round ledger:
//  * r9 proved coalesced h0 fetch cuts the stall component 33->24us, but its
//    lane remap 4x'd VALU. Here compute stays 1x (r4-verbatim).
//  * r10 proved the DMA staging mechanism but lost to 3 separable flaws, all
//    fixed here: 64KB LDS -> 2x16KB double-buffer (32KB, 5 blocks/CU, same
//    residency as r4); monolithic sync -> pipelined per-batch staging
//    (b0,b1 fly under the GEMM; b2,b3 fly under compute of b0,b1; barrier
//    drain of vmcnt verified r8); bank conflicts accepted this round
//    (~1.6us wall by r10's counter; no swizzle-bug risk at absmax==thresh).
//  * DMA has ZERO VGPR liveness -> the r5/r6/r7 sink/spill failure mode is
//    structurally impossible.
// h0 values pass through LDS unchanged; compute order r4-verbatim ->
// numerics identical. XCD swizzle omitted (r11: null — Wdt already L2-fit).
// Kill criterion: null/regression -> revert to r4, declare plateau.
// ---------------------------------------------------------------------------
__global__ __launch_bounds__(256, 5) void k3_fused(const float* __restrict__ Wdt,
                                                   const float* __restrict__ b_dt,
                                                   const float* __restrict__ x,
                                                   const float* __restrict__ A,
                                                   const float* __restrict__ Dv,
                                                   const float* __restrict__ h0,
                                                   const float* __restrict__ ws,
                                                   float* __restrict__ out) {
    __shared__ __align__(16) float buf0[256 * N_STATE];   // 16 KB
    __shared__ __align__(16) float buf1[256 * N_STATE];   // 16 KB
    const int tid  = threadIdx.x;
    const int lane = tid & 63;
    const int wv   = tid >> 6;                 // wave 0..3
    const int dblk = blockIdx.x * 256;
    const int d    = dblk + tid;
    const int b0   = blockIdx.y * K3_BT;
    const float* T  = ws + OFF_T;
    const float* SB = ws + OFF_SBC;

    // ---- DMA one batch's h0 block-slice (16 KB) into an LDS buffer.
    // Wave wv covers floats [wv*1024, wv*1024+1024) via 4 instrs; per instr
    // the global src is lane-linear (lane*16B) -> COALESCED (16 lines), and
    // the LDS dest is wave-uniform + lane*16B (HW rule). Layout in LDS ==
    // global layout: buf[d_local*16 + n].
#define STAGE_H(BI, DSTBUF)                                                   \
    {                                                                         \
        const float* sb_ = h0 + ((size_t)(b0 + (BI)) * D_INNER + dblk)        \
                           * N_STATE + wv * 1024 + lane * 4;                  \
        float* db_ = (DSTBUF) + wv * 1024;                                    \
        _Pragma("unroll")                                                     \
        for (int j2 = 0; j2 < 4; ++j2) {                                      \
            __builtin_amdgcn_global_load_lds(                                 \
                (const __attribute__((address_space(1))) void*)(sb_ + j2*256),\
                (__attribute__((address_space(3))) void*)(db_ + j2*256),      \
                16, 0, 0);                                                    \
        }                                                                     \
    }

    // ---- prologue: stage batches 0,1 (flight covered by the GEMM) ----
    STAGE_H(0, buf0)
    STAGE_H(1, buf1)

    // ---- per-thread streaming loads (r4 placement; sinking tolerated) ----
    float xv[K3_BT];
#pragma unroll
    for (int i = 0; i < K3_BT; ++i) xv[i] = x[(size_t)(b0 + i) * D_INNER + d];

    const float bdt = b_dt[d];
    const float Dd  = Dv[d];
    const float4* a4 = (const float4*)(A + (size_t)d * N_STATE);
    float4 a0 = a4[0], a1 = a4[1], a2 = a4[2], a3 = a4[3];

    // ---- delta pre-activation GEMM (r4 verbatim): DMA flies under it ----
    const float* tA = T + (size_t)b0 * KTOT;    // wave-uniform -> s_loads
    const float* tB = tA + KTOT;
    const float* tC = tB + KTOT;
    const float* tD = tC + KTOT;
    float acc[K3_BT] = {0.f, 0.f, 0.f, 0.f};
#pragma unroll 8
    for (int k = 0; k < DT_RANK; ++k) {
        float w = Wdt[(size_t)k * D_INNER + d];
        acc[0] += tA[k] * w;
        acc[1] += tB[k] * w;
        acc[2] += tC[k] * w;
        acc[3] += tD[k] * w;
    }

    __syncthreads();    // drains vmcnt (r8-verified): batches 0,1 landed

    // ---- scan body (r4-verbatim arithmetic; h0 from LDS) ----
#define SCAN_BODY(I, HBUF)                                                    \
    {                                                                         \
        const int b = b0 + (I);                                               \
        const float* Tb = T + (size_t)b * KTOT;     /* uniform -> s_loads */  \
        const float* hl = (HBUF) + tid * 16;                                  \
        float4 hc0 = *(const float4*)(hl + 0);                                \
        float4 hc1 = *(const float4*)(hl + 4);                                \
        float4 hc2 = *(const float4*)(hl + 8);                                \
        float4 hc3 = *(const float4*)(hl + 12);                               \
        float v     = acc[I] + bdt;                                           \
        float delta = (v > 20.f) ? v : log1pf(__expf(v));                     \
        float sbc   = SB[b];                                                  \
        float y0, y1, y2, y3;                                                 \
        y0  = __expf(delta * a0.x) * hc0.x * Tb[176 + 0];                     \
        y0 += __expf(delta * a0.y) * hc0.y * Tb[176 + 1];                     \
        y0 += __expf(delta * a0.z) * hc0.z * Tb[176 + 2];                     \
        y0 += __expf(delta * a0.w) * hc0.w * Tb[176 + 3];                     \
        y1  = __expf(delta * a1.x) * hc1.x * Tb[176 + 4];                     \
        y1 += __expf(delta * a1.y) * hc1.y * Tb[176 + 5];                     \
        y1 += __expf(delta * a1.z) * hc1.z * Tb[176 + 6];                     \
        y1 += __expf(delta * a1.w) * hc1.w * Tb[176 + 7];                     \
        y2  = __expf(delta * a2.x) * hc2.x * Tb[176 + 8];                     \
        y2 += __expf(delta * a2.y) * hc2.y * Tb[176 + 9];                     \
        y2 += __expf(delta * a2.z) * hc2.z * Tb[176 + 10];                    \
        y2 += __expf(delta * a2.w) * hc2.w * Tb[176 + 11];                    \
        y3  = __expf(delta * a3.x) * hc3.x * Tb[176 + 12];                    \
        y3 += __expf(delta * a3.y) * hc3.y * Tb[176 + 13];                    \
        y3 += __expf(delta * a3.z) * hc3.z * Tb[176 + 14];                    \
        y3 += __expf(delta * a3.w) * hc3.w * Tb[176 + 15];                    \
        out[(size_t)b * D_INNER + d] = xv[I] * (Dd + delta * sbc)             \
                                     + ((y0 + y1) + (y2 + y3));               \
    }

    // i=0: compute b0 from buf0; then free buf0 and stage b2 into it
    SCAN_BODY(0, buf0)
    __syncthreads();                 // all reads of buf0 done
    STAGE_H(2, buf0)                 // b2 flies under compute of b1

    // i=1: compute b1 from buf1
    SCAN_BODY(1, buf1)
    __syncthreads();                 // drains vmcnt: b2 landed; buf1 free
    STAGE_H(3, buf1)                 // b3 flies under compute of b2

    // i=2: compute b2 from buf0
    SCAN_BODY(2, buf0)
    __syncthreads();                 // drains vmcnt: b3 landed

    // i=3: compute b3 from buf1
    SCAN_BODY(3, buf1)
#undef SCAN_BODY
#undef STAGE_H
}

// ---------------------------------------------------------------------------
extern "C" void kernel_launch(void* const* d_in, const int* in_sizes, int n_in,
                              void* d_out, int out_size, void* d_ws, size_t ws_size,
                              hipStream_t stream) {
    const float* x      = (const float*)d_in[0];
    const float* Wdtlow = (const float*)d_in[1];
    const float* Wdt    = (const float*)d_in[2];
    const float* bdt    = (const float*)d_in[3];
    const float* WB     = (const float*)d_in[4];
    const float* WC     = (const float*)d_in[5];
    const float* A      = (const float*)d_in[6];
    const float* Dv     = (const float*)d_in[7];
    const float* h0     = (const float*)d_in[8];
    float* ws  = (float*)d_ws;
    float* out = (float*)d_out;

    // K1: projection GEMM partials (1024 blocks, unchanged)
    hipLaunchKernelGGL(k1_gemm, dim3(NBG, NDDB), dim3(256), 0, stream,
                       x, Wdtlow, WB, WC, ws);
    // K2: reduce partials -> T[256][192] + sbc[256]
    hipLaunchKernelGGL(k2_reduce, dim3(BATCH), dim3(192), 0, stream, ws);
    // K3: fused GEMM + scan, h0 pipelined-DMA-staged, BT=4, grid (20,64)
    hipLaunchKernelGGL(k3_fused, dim3(D_INNER / 256, BATCH / K3_BT), dim3(256),
                       0, stream, Wdt, bdt, x, A, Dv, h0, ws, out);
}